// Round 1
// baseline (210.289 us; speedup 1.0000x reference)
//
#include <hip/hip_runtime.h>

#define DEG 16
#define F_IN 128
#define H 32

typedef __attribute__((ext_vector_type(8))) _Float16 f16x8;  // MFMA A/B frag (4 VGPRs)
typedef __attribute__((ext_vector_type(4))) float f32x4;     // MFMA C/D frag
typedef __attribute__((ext_vector_type(4))) int i32x4;

union HS  { _Float16 f; unsigned short s; };
union HF4 { _Float16 h[4]; uint2 u; };

__device__ __forceinline__ float relu_f(float x) { return fmaxf(x, 0.0f); }

// packed |a| on 8 fp16 lanes: AND with 0x7FFF per half
__device__ __forceinline__ f16x8 habs8(f16x8 a) {
    union { f16x8 h; i32x4 i; } u; u.h = a;
#pragma unroll
    for (int k = 0; k < 4; ++k) u.i[k] &= 0x7FFF7FFF;
    return u.h;
}

// ---------------------------------------------------------------------------
// Pre (merged): blocks 0..31 do weight/bias prep, blocks 32.. do X fp32->fp16.
// Saves one launch; the two jobs are independent and both precede P1.
// ---------------------------------------------------------------------------
__global__ __launch_bounds__(256) void k_pre(
    const float* __restrict__ X, _Float16* __restrict__ Xh, long n8,
    const float* __restrict__ we1s, const float* __restrict__ we1p,
    const float* __restrict__ be1p, const float* __restrict__ be1s,
    const float* __restrict__ we2p, const float* __restrict__ we2s,
    const float* __restrict__ be2p, const float* __restrict__ be2s,
    const float* __restrict__ wn1p, const float* __restrict__ bn1p,
    const float* __restrict__ bn1s,
    const float* __restrict__ wn2p, const float* __restrict__ bn2p,
    const float* __restrict__ wn2s, const float* __restrict__ bn2s,
    _Float16* __restrict__ Wcat1, _Float16* __restrict__ Wcat2,
    _Float16* __restrict__ Wn1ph,
    _Float16* __restrict__ Wn2ph, _Float16* __restrict__ Wn2sh,
    float* __restrict__ bias1, float* __restrict__ bias2,
    float* __restrict__ biasn1, float* __restrict__ biasn2)
{
    if (blockIdx.x >= 32) {
        // ---- X fp32 -> fp16, one thread per 8 elements ----
        const long t = (long)(blockIdx.x - 32) * 256 + threadIdx.x;
        if (t >= n8) return;
        const float4* p = (const float4*)X + t * 2;
        const float4 a = p[0], b = p[1];
        f16x8 h;
        h[0] = (_Float16)a.x; h[1] = (_Float16)a.y; h[2] = (_Float16)a.z; h[3] = (_Float16)a.w;
        h[4] = (_Float16)b.x; h[5] = (_Float16)b.y; h[6] = (_Float16)b.z; h[7] = (_Float16)b.w;
        *(f16x8*)(Xh + t * 8) = h;
        return;
    }
    // ---- weight/bias prep (32 blocks, stride 8192) ----
    const int t0 = blockIdx.x * 256 + threadIdx.x;
    const int stride = 32 * 256;
    for (int idx = t0; idx < 32 * 192; idx += stride) {
        const int n = idx / 192, k = idx - n * 192;
        float w;
        if (k < 128)       w = we1s[n * 128 + k];
        else if (k < 160)  w = 0.5f * we1p[n * 64 + (k - 128)];
        else               w = 0.5f * we1p[n * 64 + 32 + (k - 160)];
        Wcat1[idx] = (_Float16)w;
    }
    for (int idx = t0; idx < 32 * 96; idx += stride) {
        const int n = idx / 96, k = idx - n * 96;
        float w;
        if (k < 32)       w = 0.5f * we2p[n * 64 + k];
        else if (k < 64)  w = 0.5f * we2p[n * 64 + 32 + (k - 32)];
        else              w = we2s[n * 32 + (k - 64)];
        Wcat2[idx] = (_Float16)w;
    }
    for (int idx = t0; idx < 32 * 128; idx += stride)
        Wn1ph[idx] = (_Float16)wn1p[idx];
    for (int idx = t0; idx < 32 * 32; idx += stride) {
        Wn2ph[idx] = (_Float16)wn2p[idx];
        Wn2sh[idx] = (_Float16)wn2s[idx];
    }
    if (t0 < H) {
        bias1[t0]  = be1p[t0] + be1s[t0];
        bias2[t0]  = be2p[t0] + be2s[t0];
        biasn1[t0] = bn1p[t0] + bn1s[t0];
        biasn2[t0] = bn2p[t0] + bn2s[t0];
    }
}

// ---------------------------------------------------------------------------
// P1 (4 waves / block, j-split): wave w handles j = 4w..4w+3 of a 16-node
// tile. Per-j work identical to the 1-wave version; the j-summed cn
// accumulator is reduced across waves through LDS (conflict-free [w][r][lane]
// layout). 4x wave parallelism (3125 -> 12500 waves) to hide gather latency.
// ---------------------------------------------------------------------------
__global__ __launch_bounds__(256, 3) void k_p1(
    const _Float16* __restrict__ Xh, const int* __restrict__ dst,
    const float* __restrict__ D,
    const _Float16* __restrict__ Wcat1, const _Float16* __restrict__ Wn1ph,
    const float* __restrict__ biasn1,
    _Float16* __restrict__ t1h, _Float16* __restrict__ Xn1h, int N)
{
    __shared__ float red[4][8][64];   // 8 KB: per-wave cn partials
    const int tid = threadIdx.x;
    const int lane = tid & 63;
    const int w = tid >> 6;           // wave 0..3 -> j = 4w..4w+3
    const int m = lane & 15, g = lane >> 4;
    const int i0 = blockIdx.x * 16;
    const int srow = (i0 + m < N) ? (i0 + m) : (N - 1);

    // only this wave's 4 dst indices
    const i32x4 dj = ((const i32x4*)(dst + (size_t)srow * DEG))[w];

    f16x8 sv[4];
#pragma unroll
    for (int kb = 0; kb < 4; ++kb)
        sv[kb] = *(const f16x8*)(Xh + (size_t)srow * F_IN + kb * 32 + g * 8);
    f16x8 Bs[4][2], Bn[4][2];
#pragma unroll
    for (int kb = 0; kb < 4; ++kb)
#pragma unroll
        for (int t = 0; t < 2; ++t) {
            Bs[kb][t] = *(const f16x8*)(Wcat1 + (t * 16 + m) * 192 + kb * 32 + g * 8);
            Bn[kb][t] = *(const f16x8*)(Wn1ph + (t * 16 + m) * 128 + kb * 32 + g * 8);
        }

    f16x8 tvc[4], tvn[4];
#pragma unroll
    for (int kb = 0; kb < 4; ++kb)
        tvc[kb] = *(const f16x8*)(Xh + (size_t)dj[0] * F_IN + kb * 32 + g * 8);

    f32x4 cn0 = {0.f,0.f,0.f,0.f}, cn1 = {0.f,0.f,0.f,0.f};
#pragma unroll
    for (int jj = 0; jj < 4; ++jj) {
        if (jj < 3) {
            const int dn = dj[jj + 1];
#pragma unroll
            for (int kb = 0; kb < 4; ++kb)
                tvn[kb] = *(const f16x8*)(Xh + (size_t)dn * F_IN + kb * 32 + g * 8);
        }
        f32x4 cs0 = {0.f,0.f,0.f,0.f}, cs1 = {0.f,0.f,0.f,0.f};
#pragma unroll
        for (int kb = 0; kb < 4; ++kb) {
            const f16x8 a = habs8(sv[kb] - tvc[kb]);
            cs0 = __builtin_amdgcn_mfma_f32_16x16x32_f16(a, Bs[kb][0], cs0, 0, 0, 0);
            cs1 = __builtin_amdgcn_mfma_f32_16x16x32_f16(a, Bs[kb][1], cs1, 0, 0, 0);
            cn0 = __builtin_amdgcn_mfma_f32_16x16x32_f16(a, Bn[kb][0], cn0, 0, 0, 0);
            cn1 = __builtin_amdgcn_mfma_f32_16x16x32_f16(a, Bn[kb][1], cn1, 0, 0, 0);
        }
        // t1 store: fp16 identity C-layout, 8B/lane coalesced
        const size_t tb = ((size_t)blockIdx.x * 16 + w * 4 + jj) * 512;
        HF4 a4;
#pragma unroll
        for (int r = 0; r < 4; ++r) a4.h[r] = (_Float16)cs0[r];
        *(uint2*)(t1h + tb + lane * 4) = a4.u;
#pragma unroll
        for (int r = 0; r < 4; ++r) a4.h[r] = (_Float16)cs1[r];
        *(uint2*)(t1h + tb + 256 + lane * 4) = a4.u;
#pragma unroll
        for (int kb = 0; kb < 4; ++kb) tvc[kb] = tvn[kb];
    }
    // cross-wave reduce of cn, then wave 0 stores Xn1 (C: col=m, row=g*4+r)
#pragma unroll
    for (int r = 0; r < 4; ++r) {
        red[w][r][lane]     = cn0[r];
        red[w][4 + r][lane] = cn1[r];
    }
    __syncthreads();
    if (w == 0) {
        const float bn0 = biasn1[m], bn1v = biasn1[16 + m];
#pragma unroll
        for (int r = 0; r < 4; ++r) {
            const int node = i0 + g * 4 + r;
            if (node < N) {
                const float invD = 1.0f / D[node];
                const float a0 = red[0][r][lane] + red[1][r][lane]
                               + red[2][r][lane] + red[3][r][lane];
                const float a1 = red[0][4+r][lane] + red[1][4+r][lane]
                               + red[2][4+r][lane] + red[3][4+r][lane];
                Xn1h[(size_t)node * H + m]      = (_Float16)relu_f(a0 * invD + bn0);
                Xn1h[(size_t)node * H + 16 + m] = (_Float16)relu_f(a1 * invD + bn1v);
            }
        }
    }
}

// ---------------------------------------------------------------------------
// P2 (4 waves / block, j-split): finish edge_conv1 from the sequential t1
// stream, vals1 in place over t1 (per-wave j-range -> no cross-wave hazard).
// Asum partials reduced via LDS; wave 0 computes Xn2 with 4 MFMAs.
// ---------------------------------------------------------------------------
__global__ __launch_bounds__(256, 4) void k_p2(
    const int* __restrict__ dst, const _Float16* __restrict__ Xn1h,
    const _Float16* __restrict__ Wcat1, const float* __restrict__ bias1,
    const _Float16* __restrict__ Wn2ph, const _Float16* __restrict__ Wn2sh,
    const float* __restrict__ biasn2, const float* __restrict__ D,
    _Float16* t1v1,                 // read t1, write vals1 (same buffer)
    _Float16* __restrict__ Xn2h, int N)
{
    __shared__ unsigned short RP[4][16 * 40];  // 5 KB: per-wave repack buf
    __shared__ float red[4][8][64];            // 8 KB: Asum partials
    const int tid = threadIdx.x;
    const int lane = tid & 63;
    const int w = tid >> 6;
    const int m = lane & 15, g = lane >> 4;
    const int i0 = blockIdx.x * 16;
    const int srow = (i0 + m < N) ? (i0 + m) : (N - 1);

    const i32x4 dj = ((const i32x4*)(dst + (size_t)srow * DEG))[w];
    const f16x8 x1 = *(const f16x8*)(Xn1h + (size_t)srow * H + g * 8);
    f16x8 Bf[2][2];
#pragma unroll
    for (int kb = 0; kb < 2; ++kb)
#pragma unroll
        for (int t = 0; t < 2; ++t)
            Bf[kb][t] = *(const f16x8*)(Wcat1 + (t * 16 + m) * 192 + (4 + kb) * 32 + g * 8);

    f16x8 x2c, x2n;
    uint2 u0c, u1c, u0n, u1n;
    {
        const int d0 = dj[0];
        x2c = *(const f16x8*)(Xn1h + (size_t)d0 * H + g * 8);
        const size_t tb = ((size_t)blockIdx.x * 16 + w * 4) * 512;
        u0c = *(const uint2*)(t1v1 + tb + lane * 4);
        u1c = *(const uint2*)(t1v1 + tb + 256 + lane * 4);
    }
    const float b0 = bias1[m], b1v = bias1[16 + m];
    f32x4 sB0 = {0.f,0.f,0.f,0.f}, sB1 = {0.f,0.f,0.f,0.f};
    const int rr = lane >> 2, qq = lane & 3;
    unsigned short* RPw = RP[w];
#pragma unroll
    for (int jj = 0; jj < 4; ++jj) {
        if (jj < 3) {
            const int dn = dj[jj + 1];
            x2n = *(const f16x8*)(Xn1h + (size_t)dn * H + g * 8);
            const size_t tbn = ((size_t)blockIdx.x * 16 + w * 4 + jj + 1) * 512;
            u0n = *(const uint2*)(t1v1 + tbn + lane * 4);
            u1n = *(const uint2*)(t1v1 + tbn + 256 + lane * 4);
        }
        f32x4 c0, c1;
        { HF4 a; a.u = u0c;
#pragma unroll
          for (int r = 0; r < 4; ++r) c0[r] = (float)a.h[r];
          a.u = u1c;
#pragma unroll
          for (int r = 0; r < 4; ++r) c1[r] = (float)a.h[r]; }
        const f16x8 ad = x1 - x2c;
        const f16x8 aS = x1 + x2c;
        c0 = __builtin_amdgcn_mfma_f32_16x16x32_f16(ad, Bf[0][0], c0, 0, 0, 0);
        c1 = __builtin_amdgcn_mfma_f32_16x16x32_f16(ad, Bf[0][1], c1, 0, 0, 0);
        c0 = __builtin_amdgcn_mfma_f32_16x16x32_f16(aS, Bf[1][0], c0, 0, 0, 0);
        c1 = __builtin_amdgcn_mfma_f32_16x16x32_f16(aS, Bf[1][1], c1, 0, 0, 0);
#pragma unroll
        for (int r = 0; r < 4; ++r) {
            const float v0 = relu_f(c0[r] + b0);
            const float v1 = relu_f(c1[r] + b1v);
            HS h0, h1; h0.f = (_Float16)v0; h1.f = (_Float16)v1;
            RPw[(g * 4 + r) * 40 + m]      = h0.s;
            RPw[(g * 4 + r) * 40 + 16 + m] = h1.s;
            sB0[r] += v0; sB1[r] += v1;
        }
        // repack to tile-major (intra-wave LDS dep: compiler lgkm waits)
        const size_t tb = ((size_t)blockIdx.x * 16 + w * 4 + jj) * 512;
        const i32x4 v = *(const i32x4*)(RPw + rr * 40 + qq * 8);
        *(i32x4*)(t1v1 + tb + rr * 32 + qq * 8) = v;
        x2c = x2n; u0c = u0n; u1c = u1n;
    }
    // cross-wave Asum reduce -> wave 0: transpose via RP -> A-frag -> Xn2
#pragma unroll
    for (int r = 0; r < 4; ++r) {
        red[w][r][lane]     = sB0[r];
        red[w][4 + r][lane] = sB1[r];
    }
    __syncthreads();
    if (w == 0) {
        _Float16* RPh = (_Float16*)RP[0];
#pragma unroll
        for (int r = 0; r < 4; ++r) {
            const int node = i0 + g * 4 + r;
            const float invD = 1.0f / D[(node < N) ? node : (N - 1)];
            const float a0 = red[0][r][lane] + red[1][r][lane]
                           + red[2][r][lane] + red[3][r][lane];
            const float a1 = red[0][4+r][lane] + red[1][4+r][lane]
                           + red[2][4+r][lane] + red[3][4+r][lane];
            RPh[(g * 4 + r) * 40 + m]      = (_Float16)(a0 * invD);
            RPh[(g * 4 + r) * 40 + 16 + m] = (_Float16)(a1 * invD);
        }
        const f16x8 aF = *(const f16x8*)(RPh + m * 40 + g * 8);
        f16x8 Bp[2], Bs2[2];
#pragma unroll
        for (int t = 0; t < 2; ++t) {
            Bp[t]  = *(const f16x8*)(Wn2ph + (t * 16 + m) * H + g * 8);
            Bs2[t] = *(const f16x8*)(Wn2sh + (t * 16 + m) * H + g * 8);
        }
        f32x4 c0 = {0.f,0.f,0.f,0.f}, c1 = {0.f,0.f,0.f,0.f};
        c0 = __builtin_amdgcn_mfma_f32_16x16x32_f16(aF, Bp[0], c0, 0, 0, 0);
        c1 = __builtin_amdgcn_mfma_f32_16x16x32_f16(aF, Bp[1], c1, 0, 0, 0);
        c0 = __builtin_amdgcn_mfma_f32_16x16x32_f16(x1, Bs2[0], c0, 0, 0, 0);
        c1 = __builtin_amdgcn_mfma_f32_16x16x32_f16(x1, Bs2[1], c1, 0, 0, 0);
        const float bp0 = biasn2[m], bp1 = biasn2[16 + m];
#pragma unroll
        for (int r = 0; r < 4; ++r) {
            const int node = i0 + g * 4 + r;
            if (node < N) {
                Xn2h[(size_t)node * H + m]      = (_Float16)relu_f(c0[r] + bp0);
                Xn2h[(size_t)node * H + 16 + m] = (_Float16)relu_f(c1[r] + bp1);
            }
        }
    }
}

// ---------------------------------------------------------------------------
// P3 (4 waves / block, j-split): layer-2 edge conv + classifier + sigmoid.
// Each wave: 4 j's with 2-deep prefetch ring; outS columns are per-j so the
// split is hazard-free; one barrier then 256-thread 1 KB burst store.
// ---------------------------------------------------------------------------
__global__ __launch_bounds__(256, 4) void k_p3(
    const _Float16* __restrict__ Xn2h, const int* __restrict__ dst,
    const _Float16* __restrict__ vals1,
    const _Float16* __restrict__ Wcat2, const float* __restrict__ bias2,
    const float* __restrict__ wc, const float* __restrict__ bc,
    float* __restrict__ out, int N)
{
    __shared__ float outS[16 * 16];   // [node][j], 1 KB
    const int tid = threadIdx.x;
    const int lane = tid & 63;
    const int w = tid >> 6;
    const int m = lane & 15, g = lane >> 4;
    const int i0 = blockIdx.x * 16;
    const int srow = (i0 + m < N) ? (i0 + m) : (N - 1);

    const i32x4 dj = ((const i32x4*)(dst + (size_t)srow * DEG))[w];
    const f16x8 x1 = *(const f16x8*)(Xn2h + (size_t)srow * H + g * 8);
    f16x8 Bf[3][2];
#pragma unroll
    for (int kb = 0; kb < 3; ++kb)
#pragma unroll
        for (int t = 0; t < 2; ++t)
            Bf[kb][t] = *(const f16x8*)(Wcat2 + (t * 16 + m) * 96 + kb * 32 + g * 8);

    // 2-deep prefetch ring over this wave's 4 tiles
    f16x8 x2b[2], avb[2];
#pragma unroll
    for (int s = 0; s < 2; ++s) {
        const int dn = dj[s];
        x2b[s] = *(const f16x8*)(Xn2h + (size_t)dn * H + g * 8);
        avb[s] = *(const f16x8*)(vals1 + ((size_t)blockIdx.x * 16 + w * 4 + s) * 512 + m * 32 + g * 8);
    }
    const float b0 = bias2[m], b1v = bias2[16 + m];
    const float w0 = wc[m], w1 = wc[16 + m];
#pragma unroll
    for (int jj = 0; jj < 4; ++jj) {
        const int s = jj & 1;
        const f16x8 x2 = x2b[s];
        const f16x8 av = avb[s];
        if (jj < 2) {
            const int dn = dj[jj + 2];
            x2b[s] = *(const f16x8*)(Xn2h + (size_t)dn * H + g * 8);
            avb[s] = *(const f16x8*)(vals1 + ((size_t)blockIdx.x * 16 + w * 4 + jj + 2) * 512 + m * 32 + g * 8);
        }
        const f16x8 ad = x1 - x2;
        const f16x8 aS = x1 + x2;
        f32x4 c0 = {0.f,0.f,0.f,0.f}, c1 = {0.f,0.f,0.f,0.f};
        c0 = __builtin_amdgcn_mfma_f32_16x16x32_f16(ad, Bf[0][0], c0, 0, 0, 0);
        c1 = __builtin_amdgcn_mfma_f32_16x16x32_f16(ad, Bf[0][1], c1, 0, 0, 0);
        c0 = __builtin_amdgcn_mfma_f32_16x16x32_f16(aS, Bf[1][0], c0, 0, 0, 0);
        c1 = __builtin_amdgcn_mfma_f32_16x16x32_f16(aS, Bf[1][1], c1, 0, 0, 0);
        c0 = __builtin_amdgcn_mfma_f32_16x16x32_f16(av, Bf[2][0], c0, 0, 0, 0);
        c1 = __builtin_amdgcn_mfma_f32_16x16x32_f16(av, Bf[2][1], c1, 0, 0, 0);

        float sr[4];
#pragma unroll
        for (int r = 0; r < 4; ++r)
            sr[r] = relu_f(c0[r] + b0) * w0 + relu_f(c1[r] + b1v) * w1;
#pragma unroll
        for (int mask = 1; mask < 16; mask <<= 1) {
#pragma unroll
            for (int r = 0; r < 4; ++r)
                sr[r] += __shfl_xor(sr[r], mask);
        }
        if (m == 0) {
#pragma unroll
            for (int r = 0; r < 4; ++r)
                outS[(g * 4 + r) * 16 + (w * 4 + jj)] = sr[r];
        }
    }
    __syncthreads();
    // burst store: 256 threads x float = 1 KB contiguous; tid = node*16 + j
    {
        const float bcv = bc[0];
        const float v = outS[tid];
        const float o = 1.0f / (1.0f + __expf(-(v + bcv)));
        if (i0 + 16 <= N || (i0 + (tid >> 4)) < N)
            out[(size_t)i0 * DEG + tid] = o;
    }
}

// ---------------------------------------------------------------------------
extern "C" void kernel_launch(void* const* d_in, const int* in_sizes, int n_in,
                              void* d_out, int out_size, void* d_ws, size_t ws_size,
                              hipStream_t stream)
{
    const float* X    = (const float*)d_in[0];
    const int*   dst  = (const int*)  d_in[2];
    const float* D    = (const float*)d_in[3];
    const float* wn1p = (const float*)d_in[4];
    const float* bn1p = (const float*)d_in[5];
    // d_in[6] = wn1s unused: X0 == zeros, self term reduces to bn1s.
    const float* bn1s = (const float*)d_in[7];
    const float* we1p = (const float*)d_in[8];
    const float* be1p = (const float*)d_in[9];
    const float* we1s = (const float*)d_in[10];
    const float* be1s = (const float*)d_in[11];
    const float* wn2p = (const float*)d_in[12];
    const float* bn2p = (const float*)d_in[13];
    const float* wn2s = (const float*)d_in[14];
    const float* bn2s = (const float*)d_in[15];
    const float* we2p = (const float*)d_in[16];
    const float* be2p = (const float*)d_in[17];
    const float* we2s = (const float*)d_in[18];
    const float* be2s = (const float*)d_in[19];
    const float* wc   = (const float*)d_in[20];
    const float* bc   = (const float*)d_in[21];

    const int N = in_sizes[3];        // D has one entry per node
    const int nbW = (N + 15) / 16;    // one 4-wave block per 16 nodes
    const size_t Epad = (size_t)nbW * 16 * DEG;

    // ws (~70.6 MB):
    char* w = (char*)d_ws;
    _Float16* t1v1  = (_Float16*)w;  w += Epad * H * 2;          // t1/vals1 tiles (fp16)
    _Float16* Xh    = (_Float16*)w;  w += (size_t)N * F_IN * 2;  // X fp16
    _Float16* Xn1h  = (_Float16*)w;  w += (size_t)N * H * 2;
    _Float16* Xn2h  = (_Float16*)w;  w += (size_t)N * H * 2;
    _Float16* Wcat1 = (_Float16*)w;  w += 32 * 192 * 2;
    _Float16* Wcat2 = (_Float16*)w;  w += 32 * 96 * 2;
    _Float16* Wn1ph = (_Float16*)w;  w += 32 * 128 * 2;
    _Float16* Wn2ph = (_Float16*)w;  w += 32 * 32 * 2;
    _Float16* Wn2sh = (_Float16*)w;  w += 32 * 32 * 2;
    float* bias1  = (float*)w;       w += H * 4;
    float* bias2  = (float*)w;       w += H * 4;
    float* biasn1 = (float*)w;       w += H * 4;
    float* biasn2 = (float*)w;       w += H * 4;
    float* outp = (float*)d_out;

    const long n8 = (long)N * F_IN / 8;
    const int nbX = (int)((n8 + 255) / 256);

    k_pre<<<nbX + 32, 256, 0, stream>>>(X, Xh, n8,
                                        we1s, we1p, be1p, be1s, we2p, we2s, be2p, be2s,
                                        wn1p, bn1p, bn1s, wn2p, bn2p, wn2s, bn2s,
                                        Wcat1, Wcat2, Wn1ph, Wn2ph, Wn2sh,
                                        bias1, bias2, biasn1, biasn2);
    k_p1<<<nbW, 256, 0, stream>>>(Xh, dst, D, Wcat1, Wn1ph, biasn1, t1v1, Xn1h, N);
    k_p2<<<nbW, 256, 0, stream>>>(dst, Xn1h, Wcat1, bias1, Wn2ph, Wn2sh,
                                  biasn2, D, t1v1, Xn2h, N);
    k_p3<<<nbW, 256, 0, stream>>>(Xn2h, dst, t1v1, Wcat2, bias2, wc, bc, outp, N);
}

// Round 4
// 194.489 us; speedup vs baseline: 1.0812x; 1.0812x over previous
//
#include <hip/hip_runtime.h>

#define DEG 16
#define F_IN 128
#define H 32

typedef __attribute__((ext_vector_type(8))) _Float16 f16x8;  // MFMA A/B frag (4 VGPRs)
typedef __attribute__((ext_vector_type(4))) float f32x4;     // MFMA C/D frag
typedef __attribute__((ext_vector_type(4))) int i32x4;
typedef __attribute__((ext_vector_type(4))) float fv4;       // clang vector (NT-capable)
typedef __attribute__((ext_vector_type(2))) unsigned int uv2; // clang vector (NT-capable)

union HS  { _Float16 f; unsigned short s; };
union HF4 { _Float16 h[4]; uv2 u; };

__device__ __forceinline__ float relu_f(float x) { return fmaxf(x, 0.0f); }

// packed |a| on 8 fp16 lanes: AND with 0x7FFF per half
__device__ __forceinline__ f16x8 habs8(f16x8 a) {
    union { f16x8 h; i32x4 i; } u; u.h = a;
#pragma unroll
    for (int k = 0; k < 4; ++k) u.i[k] &= 0x7FFF7FFF;
    return u.h;
}

// ---------------------------------------------------------------------------
// Pre (merged): blocks 0..31 do weight/bias prep, blocks 32.. do X fp32->fp16.
// X fp32 is read ONCE -> non-temporal load (don't pollute L3); Xh store is
// NORMAL so the fp16 X table gets primed into the Infinity Cache for P1.
// ---------------------------------------------------------------------------
__global__ __launch_bounds__(256) void k_pre(
    const float* __restrict__ X, _Float16* __restrict__ Xh, long n8,
    const float* __restrict__ we1s, const float* __restrict__ we1p,
    const float* __restrict__ be1p, const float* __restrict__ be1s,
    const float* __restrict__ we2p, const float* __restrict__ we2s,
    const float* __restrict__ be2p, const float* __restrict__ be2s,
    const float* __restrict__ wn1p, const float* __restrict__ bn1p,
    const float* __restrict__ bn1s,
    const float* __restrict__ wn2p, const float* __restrict__ bn2p,
    const float* __restrict__ wn2s, const float* __restrict__ bn2s,
    _Float16* __restrict__ Wcat1, _Float16* __restrict__ Wcat2,
    _Float16* __restrict__ Wn1ph,
    _Float16* __restrict__ Wn2ph, _Float16* __restrict__ Wn2sh,
    float* __restrict__ bias1, float* __restrict__ bias2,
    float* __restrict__ biasn1, float* __restrict__ biasn2)
{
    if (blockIdx.x >= 32) {
        // ---- X fp32 -> fp16, one thread per 8 elements ----
        const long t = (long)(blockIdx.x - 32) * 256 + threadIdx.x;
        if (t >= n8) return;
        const fv4* p = (const fv4*)X + t * 2;
        const fv4 a = __builtin_nontemporal_load(p);
        const fv4 b = __builtin_nontemporal_load(p + 1);
        f16x8 h;
        h[0] = (_Float16)a[0]; h[1] = (_Float16)a[1]; h[2] = (_Float16)a[2]; h[3] = (_Float16)a[3];
        h[4] = (_Float16)b[0]; h[5] = (_Float16)b[1]; h[6] = (_Float16)b[2]; h[7] = (_Float16)b[3];
        *(f16x8*)(Xh + t * 8) = h;
        return;
    }
    // ---- weight/bias prep (32 blocks, stride 8192) ----
    const int t0 = blockIdx.x * 256 + threadIdx.x;
    const int stride = 32 * 256;
    for (int idx = t0; idx < 32 * 192; idx += stride) {
        const int n = idx / 192, k = idx - n * 192;
        float w;
        if (k < 128)       w = we1s[n * 128 + k];
        else if (k < 160)  w = 0.5f * we1p[n * 64 + (k - 128)];
        else               w = 0.5f * we1p[n * 64 + 32 + (k - 160)];
        Wcat1[idx] = (_Float16)w;
    }
    for (int idx = t0; idx < 32 * 96; idx += stride) {
        const int n = idx / 96, k = idx - n * 96;
        float w;
        if (k < 32)       w = 0.5f * we2p[n * 64 + k];
        else if (k < 64)  w = 0.5f * we2p[n * 64 + 32 + (k - 32)];
        else              w = we2s[n * 32 + (k - 64)];
        Wcat2[idx] = (_Float16)w;
    }
    for (int idx = t0; idx < 32 * 128; idx += stride)
        Wn1ph[idx] = (_Float16)wn1p[idx];
    for (int idx = t0; idx < 32 * 32; idx += stride) {
        Wn2ph[idx] = (_Float16)wn2p[idx];
        Wn2sh[idx] = (_Float16)wn2s[idx];
    }
    if (t0 < H) {
        bias1[t0]  = be1p[t0] + be1s[t0];
        bias2[t0]  = be2p[t0] + be2s[t0];
        biasn1[t0] = bn1p[t0] + bn1s[t0];
        biasn2[t0] = bn2p[t0] + bn2s[t0];
    }
}

// ---------------------------------------------------------------------------
// P1 (1 wave / block, round-0 structure): the ONLY X pass. 16 nodes x 16 offsets.
//   t1 tile_j = |dX| @ we1s^T  -> fp16 C-layout, NON-TEMPORAL store (53 MB
//   write stream must not evict the 12.8 MB X table from L3 -- that eviction
//   was costing ~60 MB of HBM X re-fetch, FETCH_SIZE 76 MB vs ~16 MB ideal).
//   U += |dX| @ wn1p^T -> Xn1 = relu(U/D + biasn1), normal store (hot in P2).
// ---------------------------------------------------------------------------
__global__ __launch_bounds__(64, 3) void k_p1(
    const _Float16* __restrict__ Xh, const int* __restrict__ dst,
    const float* __restrict__ D,
    const _Float16* __restrict__ Wcat1, const _Float16* __restrict__ Wn1ph,
    const float* __restrict__ biasn1,
    _Float16* __restrict__ t1h, _Float16* __restrict__ Xn1h, int N)
{
    const int lane = threadIdx.x;
    const int m = lane & 15, g = lane >> 4;
    const int i0 = blockIdx.x * 16;
    const int srow = (i0 + m < N) ? (i0 + m) : (N - 1);

    i32x4 dj4[4];
    {
        const i32x4* dp = (const i32x4*)(dst + (size_t)srow * DEG);
#pragma unroll
        for (int q = 0; q < 4; ++q) dj4[q] = dp[q];
    }
    f16x8 sv[4];
#pragma unroll
    for (int kb = 0; kb < 4; ++kb)
        sv[kb] = *(const f16x8*)(Xh + (size_t)srow * F_IN + kb * 32 + g * 8);
    f16x8 Bs[4][2], Bn[4][2];
#pragma unroll
    for (int kb = 0; kb < 4; ++kb)
#pragma unroll
        for (int t = 0; t < 2; ++t) {
            Bs[kb][t] = *(const f16x8*)(Wcat1 + (t * 16 + m) * 192 + kb * 32 + g * 8);
            Bn[kb][t] = *(const f16x8*)(Wn1ph + (t * 16 + m) * 128 + kb * 32 + g * 8);
        }

    f16x8 tvc[4], tvn[4];
#pragma unroll
    for (int kb = 0; kb < 4; ++kb)
        tvc[kb] = *(const f16x8*)(Xh + (size_t)dj4[0][0] * F_IN + kb * 32 + g * 8);

    f32x4 cn0 = {0.f,0.f,0.f,0.f}, cn1 = {0.f,0.f,0.f,0.f};
#pragma unroll
    for (int j = 0; j < 16; ++j) {
        if (j < 15) {
            const int dn = dj4[(j + 1) >> 2][(j + 1) & 3];
#pragma unroll
            for (int kb = 0; kb < 4; ++kb)
                tvn[kb] = *(const f16x8*)(Xh + (size_t)dn * F_IN + kb * 32 + g * 8);
        }
        f32x4 cs0 = {0.f,0.f,0.f,0.f}, cs1 = {0.f,0.f,0.f,0.f};
#pragma unroll
        for (int kb = 0; kb < 4; ++kb) {
            const f16x8 a = habs8(sv[kb] - tvc[kb]);
            cs0 = __builtin_amdgcn_mfma_f32_16x16x32_f16(a, Bs[kb][0], cs0, 0, 0, 0);
            cs1 = __builtin_amdgcn_mfma_f32_16x16x32_f16(a, Bs[kb][1], cs1, 0, 0, 0);
            cn0 = __builtin_amdgcn_mfma_f32_16x16x32_f16(a, Bn[kb][0], cn0, 0, 0, 0);
            cn1 = __builtin_amdgcn_mfma_f32_16x16x32_f16(a, Bn[kb][1], cn1, 0, 0, 0);
        }
        // t1 store: fp16 identity C-layout, 8B/lane coalesced, NT (bypass L3)
        const size_t tb = ((size_t)blockIdx.x * 16 + j) * 512;
        HF4 a;
#pragma unroll
        for (int r = 0; r < 4; ++r) a.h[r] = (_Float16)cs0[r];
        __builtin_nontemporal_store(a.u, (uv2*)(t1h + tb + lane * 4));
#pragma unroll
        for (int r = 0; r < 4; ++r) a.h[r] = (_Float16)cs1[r];
        __builtin_nontemporal_store(a.u, (uv2*)(t1h + tb + 256 + lane * 4));
#pragma unroll
        for (int kb = 0; kb < 4; ++kb) tvc[kb] = tvn[kb];
    }
    // C layout: col = m (feature), row = g*4+r (node). Store Xn1 directly.
    const float bn0 = biasn1[m], bn1v = biasn1[16 + m];
#pragma unroll
    for (int r = 0; r < 4; ++r) {
        const int node = i0 + g * 4 + r;
        if (node < N) {
            const float invD = 1.0f / D[node];
            Xn1h[(size_t)node * H + m]      = (_Float16)relu_f(cn0[r] * invD + bn0);
            Xn1h[(size_t)node * H + 16 + m] = (_Float16)relu_f(cn1[r] * invD + bn1v);
        }
    }
}

// ---------------------------------------------------------------------------
// P2 (4 waves / block, j-split -- this split measured faster for the small
// 64 B Xn1 gathers): finish edge_conv1 from the sequential t1 stream.
// t1 reads are read-once -> non-temporal loads (keep L3 for vals1, which P3
// re-reads). vals1 stores stay NORMAL so P3 reads from L3.
// ---------------------------------------------------------------------------
__global__ __launch_bounds__(256, 4) void k_p2(
    const int* __restrict__ dst, const _Float16* __restrict__ Xn1h,
    const _Float16* __restrict__ Wcat1, const float* __restrict__ bias1,
    const _Float16* __restrict__ Wn2ph, const _Float16* __restrict__ Wn2sh,
    const float* __restrict__ biasn2, const float* __restrict__ D,
    _Float16* t1v1,                 // read t1, write vals1 (same buffer)
    _Float16* __restrict__ Xn2h, int N)
{
    __shared__ unsigned short RP[4][16 * 40];  // 5 KB: per-wave repack buf
    __shared__ float red[4][8][64];            // 8 KB: Asum partials
    const int tid = threadIdx.x;
    const int lane = tid & 63;
    const int w = tid >> 6;
    const int m = lane & 15, g = lane >> 4;
    const int i0 = blockIdx.x * 16;
    const int srow = (i0 + m < N) ? (i0 + m) : (N - 1);

    const i32x4 dj = ((const i32x4*)(dst + (size_t)srow * DEG))[w];
    const f16x8 x1 = *(const f16x8*)(Xn1h + (size_t)srow * H + g * 8);
    f16x8 Bf[2][2];
#pragma unroll
    for (int kb = 0; kb < 2; ++kb)
#pragma unroll
        for (int t = 0; t < 2; ++t)
            Bf[kb][t] = *(const f16x8*)(Wcat1 + (t * 16 + m) * 192 + (4 + kb) * 32 + g * 8);

    f16x8 x2c, x2n;
    uv2 u0c, u1c, u0n, u1n;
    {
        const int d0 = dj[0];
        x2c = *(const f16x8*)(Xn1h + (size_t)d0 * H + g * 8);
        const size_t tb = ((size_t)blockIdx.x * 16 + w * 4) * 512;
        u0c = __builtin_nontemporal_load((const uv2*)(t1v1 + tb + lane * 4));
        u1c = __builtin_nontemporal_load((const uv2*)(t1v1 + tb + 256 + lane * 4));
    }
    const float b0 = bias1[m], b1v = bias1[16 + m];
    f32x4 sB0 = {0.f,0.f,0.f,0.f}, sB1 = {0.f,0.f,0.f,0.f};
    const int rr = lane >> 2, qq = lane & 3;
    unsigned short* RPw = RP[w];
#pragma unroll
    for (int jj = 0; jj < 4; ++jj) {
        if (jj < 3) {
            const int dn = dj[jj + 1];
            x2n = *(const f16x8*)(Xn1h + (size_t)dn * H + g * 8);
            const size_t tbn = ((size_t)blockIdx.x * 16 + w * 4 + jj + 1) * 512;
            u0n = __builtin_nontemporal_load((const uv2*)(t1v1 + tbn + lane * 4));
            u1n = __builtin_nontemporal_load((const uv2*)(t1v1 + tbn + 256 + lane * 4));
        }
        f32x4 c0, c1;
        { HF4 a; a.u = u0c;
#pragma unroll
          for (int r = 0; r < 4; ++r) c0[r] = (float)a.h[r];
          a.u = u1c;
#pragma unroll
          for (int r = 0; r < 4; ++r) c1[r] = (float)a.h[r]; }
        const f16x8 ad = x1 - x2c;
        const f16x8 aS = x1 + x2c;
        c0 = __builtin_amdgcn_mfma_f32_16x16x32_f16(ad, Bf[0][0], c0, 0, 0, 0);
        c1 = __builtin_amdgcn_mfma_f32_16x16x32_f16(ad, Bf[0][1], c1, 0, 0, 0);
        c0 = __builtin_amdgcn_mfma_f32_16x16x32_f16(aS, Bf[1][0], c0, 0, 0, 0);
        c1 = __builtin_amdgcn_mfma_f32_16x16x32_f16(aS, Bf[1][1], c1, 0, 0, 0);
#pragma unroll
        for (int r = 0; r < 4; ++r) {
            const float v0 = relu_f(c0[r] + b0);
            const float v1 = relu_f(c1[r] + b1v);
            HS h0, h1; h0.f = (_Float16)v0; h1.f = (_Float16)v1;
            RPw[(g * 4 + r) * 40 + m]      = h0.s;
            RPw[(g * 4 + r) * 40 + 16 + m] = h1.s;
            sB0[r] += v0; sB1[r] += v1;
        }
        // repack to tile-major (intra-wave LDS dep: compiler lgkm waits)
        const size_t tb = ((size_t)blockIdx.x * 16 + w * 4 + jj) * 512;
        const i32x4 v = *(const i32x4*)(RPw + rr * 40 + qq * 8);
        *(i32x4*)(t1v1 + tb + rr * 32 + qq * 8) = v;
        x2c = x2n; u0c = u0n; u1c = u1n;
    }
    // cross-wave Asum reduce -> wave 0: transpose via RP -> A-frag -> Xn2
#pragma unroll
    for (int r = 0; r < 4; ++r) {
        red[w][r][lane]     = sB0[r];
        red[w][4 + r][lane] = sB1[r];
    }
    __syncthreads();
    if (w == 0) {
        _Float16* RPh = (_Float16*)RP[0];
#pragma unroll
        for (int r = 0; r < 4; ++r) {
            const int node = i0 + g * 4 + r;
            const float invD = 1.0f / D[(node < N) ? node : (N - 1)];
            const float a0 = red[0][r][lane] + red[1][r][lane]
                           + red[2][r][lane] + red[3][r][lane];
            const float a1 = red[0][4+r][lane] + red[1][4+r][lane]
                           + red[2][4+r][lane] + red[3][4+r][lane];
            RPh[(g * 4 + r) * 40 + m]      = (_Float16)(a0 * invD);
            RPh[(g * 4 + r) * 40 + 16 + m] = (_Float16)(a1 * invD);
        }
        const f16x8 aF = *(const f16x8*)(RPh + m * 40 + g * 8);
        f16x8 Bp[2], Bs2[2];
#pragma unroll
        for (int t = 0; t < 2; ++t) {
            Bp[t]  = *(const f16x8*)(Wn2ph + (t * 16 + m) * H + g * 8);
            Bs2[t] = *(const f16x8*)(Wn2sh + (t * 16 + m) * H + g * 8);
        }
        f32x4 c0 = {0.f,0.f,0.f,0.f}, c1 = {0.f,0.f,0.f,0.f};
        c0 = __builtin_amdgcn_mfma_f32_16x16x32_f16(aF, Bp[0], c0, 0, 0, 0);
        c1 = __builtin_amdgcn_mfma_f32_16x16x32_f16(aF, Bp[1], c1, 0, 0, 0);
        c0 = __builtin_amdgcn_mfma_f32_16x16x32_f16(x1, Bs2[0], c0, 0, 0, 0);
        c1 = __builtin_amdgcn_mfma_f32_16x16x32_f16(x1, Bs2[1], c1, 0, 0, 0);
        const float bp0 = biasn2[m], bp1 = biasn2[16 + m];
#pragma unroll
        for (int r = 0; r < 4; ++r) {
            const int node = i0 + g * 4 + r;
            if (node < N) {
                Xn2h[(size_t)node * H + m]      = (_Float16)relu_f(c0[r] + bp0);
                Xn2h[(size_t)node * H + 16 + m] = (_Float16)relu_f(c1[r] + bp1);
            }
        }
    }
}

// ---------------------------------------------------------------------------
// P3 (4 waves / block, j-split): layer-2 edge conv + classifier + sigmoid.
// Each wave: 4 j's with 2-deep prefetch ring; one barrier then burst store.
// ---------------------------------------------------------------------------
__global__ __launch_bounds__(256, 4) void k_p3(
    const _Float16* __restrict__ Xn2h, const int* __restrict__ dst,
    const _Float16* __restrict__ vals1,
    const _Float16* __restrict__ Wcat2, const float* __restrict__ bias2,
    const float* __restrict__ wc, const float* __restrict__ bc,
    float* __restrict__ out, int N)
{
    __shared__ float outS[16 * 16];   // [node][j], 1 KB
    const int tid = threadIdx.x;
    const int lane = tid & 63;
    const int w = tid >> 6;
    const int m = lane & 15, g = lane >> 4;
    const int i0 = blockIdx.x * 16;
    const int srow = (i0 + m < N) ? (i0 + m) : (N - 1);

    const i32x4 dj = ((const i32x4*)(dst + (size_t)srow * DEG))[w];
    const f16x8 x1 = *(const f16x8*)(Xn2h + (size_t)srow * H + g * 8);
    f16x8 Bf[3][2];
#pragma unroll
    for (int kb = 0; kb < 3; ++kb)
#pragma unroll
        for (int t = 0; t < 2; ++t)
            Bf[kb][t] = *(const f16x8*)(Wcat2 + (t * 16 + m) * 96 + kb * 32 + g * 8);

    // 2-deep prefetch ring over this wave's 4 tiles
    f16x8 x2b[2], avb[2];
#pragma unroll
    for (int s = 0; s < 2; ++s) {
        const int dn = dj[s];
        x2b[s] = *(const f16x8*)(Xn2h + (size_t)dn * H + g * 8);
        avb[s] = *(const f16x8*)(vals1 + ((size_t)blockIdx.x * 16 + w * 4 + s) * 512 + m * 32 + g * 8);
    }
    const float b0 = bias2[m], b1v = bias2[16 + m];
    const float w0 = wc[m], w1 = wc[16 + m];
#pragma unroll
    for (int jj = 0; jj < 4; ++jj) {
        const int s = jj & 1;
        const f16x8 x2 = x2b[s];
        const f16x8 av = avb[s];
        if (jj < 2) {
            const int dn = dj[jj + 2];
            x2b[s] = *(const f16x8*)(Xn2h + (size_t)dn * H + g * 8);
            avb[s] = *(const f16x8*)(vals1 + ((size_t)blockIdx.x * 16 + w * 4 + jj + 2) * 512 + m * 32 + g * 8);
        }
        const f16x8 ad = x1 - x2;
        const f16x8 aS = x1 + x2;
        f32x4 c0 = {0.f,0.f,0.f,0.f}, c1 = {0.f,0.f,0.f,0.f};
        c0 = __builtin_amdgcn_mfma_f32_16x16x32_f16(ad, Bf[0][0], c0, 0, 0, 0);
        c1 = __builtin_amdgcn_mfma_f32_16x16x32_f16(ad, Bf[0][1], c1, 0, 0, 0);
        c0 = __builtin_amdgcn_mfma_f32_16x16x32_f16(aS, Bf[1][0], c0, 0, 0, 0);
        c1 = __builtin_amdgcn_mfma_f32_16x16x32_f16(aS, Bf[1][1], c1, 0, 0, 0);
        c0 = __builtin_amdgcn_mfma_f32_16x16x32_f16(av, Bf[2][0], c0, 0, 0, 0);
        c1 = __builtin_amdgcn_mfma_f32_16x16x32_f16(av, Bf[2][1], c1, 0, 0, 0);

        float sr[4];
#pragma unroll
        for (int r = 0; r < 4; ++r)
            sr[r] = relu_f(c0[r] + b0) * w0 + relu_f(c1[r] + b1v) * w1;
#pragma unroll
        for (int mask = 1; mask < 16; mask <<= 1) {
#pragma unroll
            for (int r = 0; r < 4; ++r)
                sr[r] += __shfl_xor(sr[r], mask);
        }
        if (m == 0) {
#pragma unroll
            for (int r = 0; r < 4; ++r)
                outS[(g * 4 + r) * 16 + (w * 4 + jj)] = sr[r];
        }
    }
    __syncthreads();
    // burst store: 256 threads x float = 1 KB contiguous; tid = node*16 + j
    {
        const float bcv = bc[0];
        const float v = outS[tid];
        const float o = 1.0f / (1.0f + __expf(-(v + bcv)));
        if (i0 + 16 <= N || (i0 + (tid >> 4)) < N)
            out[(size_t)i0 * DEG + tid] = o;
    }
}

// ---------------------------------------------------------------------------
extern "C" void kernel_launch(void* const* d_in, const int* in_sizes, int n_in,
                              void* d_out, int out_size, void* d_ws, size_t ws_size,
                              hipStream_t stream)
{
    const float* X    = (const float*)d_in[0];
    const int*   dst  = (const int*)  d_in[2];
    const float* D    = (const float*)d_in[3];
    const float* wn1p = (const float*)d_in[4];
    const float* bn1p = (const float*)d_in[5];
    // d_in[6] = wn1s unused: X0 == zeros, self term reduces to bn1s.
    const float* bn1s = (const float*)d_in[7];
    const float* we1p = (const float*)d_in[8];
    const float* be1p = (const float*)d_in[9];
    const float* we1s = (const float*)d_in[10];
    const float* be1s = (const float*)d_in[11];
    const float* wn2p = (const float*)d_in[12];
    const float* bn2p = (const float*)d_in[13];
    const float* wn2s = (const float*)d_in[14];
    const float* bn2s = (const float*)d_in[15];
    const float* we2p = (const float*)d_in[16];
    const float* be2p = (const float*)d_in[17];
    const float* we2s = (const float*)d_in[18];
    const float* be2s = (const float*)d_in[19];
    const float* wc   = (const float*)d_in[20];
    const float* bc   = (const float*)d_in[21];

    const int N = in_sizes[3];        // D has one entry per node
    const int nbW = (N + 15) / 16;    // one tile per 16 nodes
    const size_t Epad = (size_t)nbW * 16 * DEG;

    // ws (~70.6 MB):
    char* w = (char*)d_ws;
    _Float16* t1v1  = (_Float16*)w;  w += Epad * H * 2;          // t1/vals1 tiles (fp16)
    _Float16* Xh    = (_Float16*)w;  w += (size_t)N * F_IN * 2;  // X fp16
    _Float16* Xn1h  = (_Float16*)w;  w += (size_t)N * H * 2;
    _Float16* Xn2h  = (_Float16*)w;  w += (size_t)N * H * 2;
    _Float16* Wcat1 = (_Float16*)w;  w += 32 * 192 * 2;
    _Float16* Wcat2 = (_Float16*)w;  w += 32 * 96 * 2;
    _Float16* Wn1ph = (_Float16*)w;  w += 32 * 128 * 2;
    _Float16* Wn2ph = (_Float16*)w;  w += 32 * 32 * 2;
    _Float16* Wn2sh = (_Float16*)w;  w += 32 * 32 * 2;
    float* bias1  = (float*)w;       w += H * 4;
    float* bias2  = (float*)w;       w += H * 4;
    float* biasn1 = (float*)w;       w += H * 4;
    float* biasn2 = (float*)w;       w += H * 4;
    float* outp = (float*)d_out;

    const long n8 = (long)N * F_IN / 8;
    const int nbX = (int)((n8 + 255) / 256);

    k_pre<<<nbX + 32, 256, 0, stream>>>(X, Xh, n8,
                                        we1s, we1p, be1p, be1s, we2p, we2s, be2p, be2s,
                                        wn1p, bn1p, bn1s, wn2p, bn2p, wn2s, bn2s,
                                        Wcat1, Wcat2, Wn1ph, Wn2ph, Wn2sh,
                                        bias1, bias2, biasn1, biasn2);
    k_p1<<<nbW, 64, 0, stream>>>(Xh, dst, D, Wcat1, Wn1ph, biasn1, t1v1, Xn1h, N);
    k_p2<<<nbW, 256, 0, stream>>>(dst, Xn1h, Wcat1, bias1, Wn2ph, Wn2sh,
                                  biasn2, D, t1v1, Xn2h, N);
    k_p3<<<nbW, 256, 0, stream>>>(Xn2h, dst, t1v1, Wcat2, bias2, wc, bc, outp, N);
}